// Round 18
// baseline (202.137 us; speedup 1.0000x reference)
//
#include <hip/hip_runtime.h>
#include <hip/hip_bf16.h>
#include <math.h>

typedef __hip_bfloat16 bf16;
typedef __attribute__((ext_vector_type(8))) short s8v;   // 8 bf16 (4 VGPRs)
typedef __attribute__((ext_vector_type(4))) float f4v;

#define B_   16
#define T_   1024
#define C_   512
#define M_   (B_*T_)      // 16384
#define NW_  4
#define KWIN 25
#define TCHUNK 16
#define NCHUNK (T_/TCHUNK)   // 64

__device__ __forceinline__ float b2f(bf16 v){ return __bfloat162float(v); }
__device__ __forceinline__ bf16  f2b(float v){ return __float2bfloat16(v); }

__device__ __forceinline__ float ftanh(float x){
    float e = __expf(2.f * x);
    return 1.f - 2.f * __builtin_amdgcn_rcpf(e + 1.f);
}
__device__ __forceinline__ float fsig(float x){
    return __builtin_amdgcn_rcpf(1.f + __expf(-x));
}

// async global->LDS, 16B per lane
__device__ __forceinline__ void gload16(const bf16* g, bf16* l) {
    __builtin_amdgcn_global_load_lds(
        (const __attribute__((address_space(1))) void*)g,
        (__attribute__((address_space(3))) void*)l, 16, 0, 0);
}

// ---------------------------------------------------------------- K0: prep (blocks 0..1535) + decomp (blocks 1536..2559)
__global__ __launch_bounds__(256) void front_kernel(
    const float* __restrict__ wav,  const float* __restrict__ ampw,
    const float* __restrict__ cheby,
    const float* __restrict__ x,
    const float* __restrict__ tcw, const float* __restrict__ tcb,
    const float* __restrict__ scw, const float* __restrict__ scb,
    const float* __restrict__ lcw, const float* __restrict__ lcb,
    bf16* __restrict__ WWT, bf16* __restrict__ AWT, bf16* __restrict__ CCT,
    float* __restrict__ bias0_part,
    bf16* __restrict__ xt, bf16* __restrict__ sctx,
    float* __restrict__ slope_part, float* __restrict__ value_part)
{
    const int blk = blockIdx.x;

    if (blk < 1536) {
        // ================= PREP =================
        __shared__ float t0[32][33], t1[32][33], t2[32][33], t3[32][33];
        const int tx = threadIdx.x & 31, ty = threadIdx.x >> 5;

        if (blk < 1280) {
            const int z = blk >> 8, rem = blk & 255;
            const int ct = (rem & 15) * 32, ot = (rem >> 4) * 32;
            const float* src = (z < 4) ? wav + (size_t)z * 262144 : ampw;
            #pragma unroll
            for (int r = 0; r < 32; r += 8)
                t0[ty + r][tx] = src[(size_t)(ct + ty + r) * 512 + ot + tx];
            __syncthreads();
            #pragma unroll
            for (int r = 0; r < 32; r += 8) {
                int o = ot + ty + r, c = ct + tx;
                bf16 v = f2b(t0[tx][ty + r]);
                if (z < 4) WWT[(size_t)o * 2048 + z * 512 + c] = v;
                else       AWT[(size_t)o * 512 + c] = v;
            }
        } else {
            const int rem = blk - 1280;
            const int ct = (rem & 15) * 32, ot = (rem >> 4) * 32;
            #pragma unroll
            for (int r = 0; r < 32; r += 8) {
                float4 w = *(const float4*)&cheby[(size_t)(ct + ty + r) * 2048 + (size_t)(ot + tx) * 4];
                t0[ty + r][tx] = w.x - w.z;
                t1[ty + r][tx] = w.y - 3.f * w.w;
                t2[ty + r][tx] = 2.f * w.z;
                t3[ty + r][tx] = 4.f * w.w;
            }
            __syncthreads();
            #pragma unroll
            for (int r = 0; r < 32; r += 8) {
                int o = ot + ty + r, c = ct + tx;
                size_t base = (size_t)o * 1536 + c;
                CCT[base]        = f2b(t1[tx][ty + r]);
                CCT[base + 512]  = f2b(t2[tx][ty + r]);
                CCT[base + 1024] = f2b(t3[tx][ty + r]);
            }
            if (threadIdx.x < 32) {
                float s = 0.f;
                #pragma unroll
                for (int cr = 0; cr < 32; ++cr) s += t0[cr][threadIdx.x];
                bias0_part[(size_t)(rem & 15) * 512 + ot + threadIdx.x] = s;
            }
        }
        return;
    }

    // ================= DECOMP =================
    const int dblk  = blk - 1536;
    const int c     = threadIdx.x * 2;
    const int chunk = dblk & 63;
    const int b     = dblk >> 6;
    const int t0i   = chunk * TCHUNK;
    const float* xb = x + (size_t)b * T_ * C_ + c;

    float w0t[2], w1t_[2], w2t[2], bt[2], w0s[2], w1s[2], w2s[2], bs[2], w0l[2], w1l[2], w2l[2], bl[2];
    #pragma unroll
    for (int e = 0; e < 2; ++e) {
        w0t[e]=tcw[(c+e)*3+0]; w1t_[e]=tcw[(c+e)*3+1]; w2t[e]=tcw[(c+e)*3+2]; bt[e]=tcb[c+e];
        w0s[e]=scw[(c+e)*3+0]; w1s[e]=scw[(c+e)*3+1]; w2s[e]=scw[(c+e)*3+2]; bs[e]=scb[c+e];
        w0l[e]=lcw[(c+e)*3+0]; w1l[e]=lcw[(c+e)*3+1]; w2l[e]=lcw[(c+e)*3+2]; bl[e]=lcb[c+e];
    }

    const float inv = 1.f / KWIN;
    float S0 = 0.f, S1 = 0.f;
    float trm[2], tr0[2], xm[2], x0v[2], sAcc[2] = {0.f,0.f}, vAcc[2] = {0.f,0.f};

    auto BODY = [&](int t, float2 an, float2 dn, bool adv) {
        float trp[2], xp[2];
        if (adv) {
            S0 += an.x - dn.x; S1 += an.y - dn.y;
            trp[0] = S0 * inv; trp[1] = S1 * inv;
            xp[0] = an.x; xp[1] = an.y;
        } else {
            trp[0] = tr0[0]; trp[1] = tr0[1];
            xp[0] = x0v[0];  xp[1] = x0v[1];
        }
        union { bf16 h[2]; unsigned u; } u1, usc;
        #pragma unroll
        for (int e = 0; e < 2; ++e) {
            float tctx = w0t[e]*trm[e] + w1t_[e]*tr0[e] + w2t[e]*trp[e] + bt[e];
            float sm = xm[e]-trm[e], s0 = x0v[e]-tr0[e], sp = xp[e]-trp[e];
            float sv = w0s[e]*sm + w1s[e]*s0 + w2s[e]*sp + bs[e];
            float sl = w0l[e]*trm[e] + w1l[e]*tr0[e] + w2l[e]*trp[e] + bl[e];
            sAcc[e] += sl; vAcc[e] += tr0[e];
            u1.h[e] = f2b(ftanh(tctx)); usc.h[e] = f2b(sv);
            trm[e] = tr0[e]; tr0[e] = trp[e]; xm[e] = x0v[e]; x0v[e] = xp[e];
        }
        size_t m = (size_t)b * T_ + t;
        *(unsigned*)&xt[m * C_ + c]   = u1.u;
        *(unsigned*)&sctx[m * C_ + c] = usc.u;
    };

    if (chunk >= 2 && chunk <= NCHUNK - 2) {
        const float* p = xb + (size_t)(t0i - KWIN) * C_;
        #pragma unroll
        for (int i = 0; i < KWIN; ++i) {
            float2 v = *(const float2*)(p + (size_t)i * C_);
            S0 += v.x; S1 += v.y;
        }
        trm[0] = S0 * inv; trm[1] = S1 * inv;
        float2 a = *(const float2*)(p + (size_t)KWIN * C_);
        float2 d = *(const float2*)p;
        S0 += a.x - d.x; S1 += a.y - d.y;
        tr0[0] = S0 * inv; tr0[1] = S1 * inv;
        float2 vm = *(const float2*)(p + (size_t)(KWIN - 1) * C_);
        xm[0] = vm.x; xm[1] = vm.y;
        x0v[0] = a.x; x0v[1] = a.y;

        #pragma unroll
        for (int tt = 0; tt < TCHUNK; ++tt) {
            float2 an = *(const float2*)(p + (size_t)(KWIN + 1 + tt) * C_);
            float2 dn = *(const float2*)(p + (size_t)(1 + tt) * C_);
            BODY(t0i + tt, an, dn, true);
        }
    } else {
        auto X = [&](int i) -> float2 {
            i = i < 0 ? 0 : (i > T_ - 1 ? T_ - 1 : i);
            return *(const float2*)&xb[(size_t)i * C_];
        };
        int j0 = (t0i > 0) ? (t0i - 1) : 0;
        #pragma unroll
        for (int i = j0 - (KWIN - 1); i <= j0; ++i) { float2 v = X(i); S0 += v.x; S1 += v.y; }
        trm[0] = S0 * inv; trm[1] = S1 * inv;
        if (t0i > 0) {
            float2 a = X(t0i), d = X(t0i - KWIN);
            S0 += a.x - d.x; S1 += a.y - d.y;
            tr0[0] = S0 * inv; tr0[1] = S1 * inv;
        } else { tr0[0] = trm[0]; tr0[1] = trm[1]; }
        { float2 v = X(t0i - 1); xm[0] = v.x; xm[1] = v.y; }
        { float2 v = X(t0i);     x0v[0] = v.x; x0v[1] = v.y; }

        #pragma unroll
        for (int tt = 0; tt < TCHUNK; ++tt) {
            int t = t0i + tt, tn = t + 1;
            bool adv = (tn <= T_ - 1);
            float2 an = make_float2(0.f, 0.f), dn = make_float2(0.f, 0.f);
            if (adv) { an = X(tn); dn = X(tn - KWIN); }
            BODY(t, an, dn, adv);
        }
    }
    int pidx = (chunk * B_ + b) * C_ + c;
    *(float2*)&slope_part[pidx] = make_float2(sAcc[0], sAcc[1]);
    *(float2*)&value_part[pidx] = make_float2(vAcc[0], vAcc[1]);
}

// ---------------------------------------------------------------- Fused big GEMM: 8-wave 128x256 PIPELINED + compacted segs.
// mode1 preamble computes the WHOLE hypernet block-locally (pool -> h -> params -> dyn -> psi -> alive):
// 8 output scalars per batch, redundantly per block, hidden in mode1's slack vs mode0's 24-iter critical path.
__global__ __launch_bounds__(512, 4) void gemm_big_kernel(
    const bf16* __restrict__ xt, const bf16* __restrict__ sctxg,
    const bf16* __restrict__ CCT, const bf16* __restrict__ WWT,
    const float* __restrict__ slope_part, const float* __restrict__ value_part,
    const float* __restrict__ hw1, const float* __restrict__ hb1,
    const float* __restrict__ hw2, const float* __restrict__ hb2,
    const float* __restrict__ bias0_part,
    bf16* __restrict__ tout, bf16* __restrict__ sout)
{
    __shared__ bf16 lA[128 * 64];        // 16 KB (also preamble reduction scratch)
    __shared__ bf16 lB[2][256 * 64];     // 64 KB double-buffered (lB[0] = preamble float scratch)

    const int lin = blockIdx.x;
    const int swz = ((lin & 7) << 6) + (lin >> 3);   // bijective XCD swizzle, 512 blocks
    const int mode = swz & 1;
    const int rem = swz >> 1;
    const int nb = rem & 1, mb = rem >> 1;
    const int m0 = mb << 7, n0 = nb << 8;

    const bf16* Ap = mode ? sctxg : xt;   // both [M][512]
    const bf16* Bp = mode ? WWT : CCT;
    bf16* Cp = mode ? sout : tout;
    const int K = mode ? 2048 : 1536;

    const int tid = threadIdx.x;
    const int lane = tid & 63, wvi = tid >> 6;
    const int wr = wvi >> 2, wc = wvi & 3;          // 2m x 4n waves of 64x64
    const int r16 = lane & 15, g = lane >> 4;
    const int row8 = lane >> 3, sl8 = lane & 7;
    const int arow = tid >> 2, quad = tid & 3;      // A staging: 4 thr/row, 16 elems each

    // ---- mode1 preamble: block-local hypernet + psi + alive ----
    float4 p4 = make_float4(0.f, 0.f, 0.f, 0.f);
    int ordPacked = 0x210, nIter = 24;              // mode0: segments {0,1,2}
    if (mode) {
        float* pcs = (float*)&lB[0][0];             // [1024] pooled features
        float* hsh = pcs + 1024;                    // [512]  hidden
        float* dsh = hsh + 512;                     // [8]    raw params
        const int bIdx = m0 >> 10;

        // pool (same serial ch order as before: bitwise-stable)
        {
            float s0 = 0.f, s1 = 0.f;
            #pragma unroll 8
            for (int ch = 0; ch < NCHUNK; ++ch) {
                s0 += slope_part[(size_t)(ch * B_ + bIdx) * 512 + tid];
                s1 += value_part[(size_t)(ch * B_ + bIdx) * 512 + tid];
            }
            pcs[tid]       = s0 * (1.f / T_);
            pcs[tid + 512] = s1 * (1.f / T_);
        }
        __syncthreads();
        // h[o] = silu(b1[o] + sum_j pcs[j]*hw1[j][o])  (coalesced over o)
        {
            float acc = hb1[tid];
            #pragma unroll 4
            for (int j = 0; j < 1024; ++j)
                acc += pcs[j] * hw1[(size_t)j * 512 + tid];
            hsh[tid] = acc * fsig(acc);   // silu
        }
        __syncthreads();
        if (tid < 8) {
            float acc = hb2[tid];
            for (int j = 0; j < 512; ++j) acc += hsh[j] * hw2[j * 8 + tid];
            dsh[tid] = acc;
        }
        __syncthreads();

        // psi per-thread from dsh + per-w alive reduction
        int* wmaxsh = (int*)lA;
        if (tid < 4) wmaxsh[tid] = 0;
        __syncthreads();
        const float tpos = (float)((m0 + arow) & 1023);
        float pv[4], am[4];
        #pragma unroll
        for (int w = 0; w < 4; ++w) {
            float pa = dsh[2 * w], pb = dsh[2 * w + 1];
            float da = fmaxf(pa, 0.f) + log1pf(__expf(-fabsf(pa))) + 0.01f;  // softplus + 0.01
            float db = fsig(pb) * (float)T_;
            float z = (tpos - db) / da;
            float z2 = z * z;
            pv[w] = (1.f - z2) * __expf(-0.5f * z2);
            am[w] = fabsf(pv[w]);
        }
        p4 = make_float4(pv[0], pv[1], pv[2], pv[3]);
        #pragma unroll
        for (int off = 32; off >= 1; off >>= 1)
            #pragma unroll
            for (int w = 0; w < 4; ++w) am[w] = fmaxf(am[w], __shfl_xor(am[w], off));
        if (lane == 0) {
            #pragma unroll
            for (int w = 0; w < 4; ++w) atomicMax(&wmaxsh[w], __float_as_int(am[w]));
        }
        __syncthreads();
        ordPacked = 0; int na = 0;
        #pragma unroll
        for (int w = 0; w < 4; ++w) {
            float f = __int_as_float(__builtin_amdgcn_readfirstlane(wmaxsh[w]));
            if (f > 1e-6f) { ordPacked |= w << (4 * na); ++na; }
        }
        nIter = na * 8;
        __syncthreads();   // all preamble LDS reads done before lB[0] DMA / lA ds_writes
    }

    auto ktOf = [&](int kidx) -> int {
        int seg = (ordPacked >> ((kidx >> 3) * 4)) & 15;
        return seg * 8 + (kidx & 7);
    };

    const bf16* srcA = Ap + (size_t)(m0 + arow) * 512 + quad * 16;

    f4v acc[4][4];
    #pragma unroll
    for (int i = 0; i < 4; ++i)
        #pragma unroll
        for (int j = 0; j < 4; ++j) acc[i][j] = (f4v)0.f;

    if (nIter > 0) {
        // ---- prologue: A(k0) regs + B(k0) DMA ----
        const int ktp = ktOf(0);
        s8v av0 = *(const s8v*)(srcA + ((ktp << 6) & 511));
        s8v av1 = *(const s8v*)(srcA + ((ktp << 6) & 511) + 8);
        #pragma unroll
        for (int c2 = 0; c2 < 4; ++c2) {
            int rb = c2 * 8 + wvi;
            int r = rb * 8 + row8;
            int ls = sl8 ^ (r & 7);
            gload16(Bp + (size_t)(n0 + r) * K + (ktp << 6) + ls * 8, &lB[0][rb * 512]);
        }
        asm volatile("s_waitcnt vmcnt(4)" ::: "memory");   // A regs landed; B(k0) in flight

        for (int kidx = 0; kidx < nIter; ++kidx) {
            const int ktc = ktOf(kidx);
            const int wsel = ktc >> 3;
            const float sc = wsel == 0 ? p4.x : wsel == 1 ? p4.y : wsel == 2 ? p4.z : p4.w;

            // (1) transform A regs -> swizzled ds_write into lA
            #pragma unroll
            for (int j2 = 0; j2 < 2; ++j2) {
                s8v a = j2 ? av1 : av0;
                s8v ov;
                if (mode == 0) {
                    if (wsel == 0) ov = a;
                    else {
                        #pragma unroll
                        for (int e = 0; e < 8; ++e) {
                            float v = b2f(((const bf16*)&a)[e]);
                            float vv = v * v;
                            ((bf16*)&ov)[e] = f2b(wsel == 1 ? vv : vv * v);
                        }
                    }
                } else {
                    #pragma unroll
                    for (int e = 0; e < 8; ++e)
                        ((bf16*)&ov)[e] = f2b(b2f(((const bf16*)&a)[e]) * sc);
                }
                int q = quad * 2 + j2;
                *(s8v*)&lA[arow * 64 + ((q ^ (arow & 7)) << 3)] = ov;
            }

            // (2) prefetch A(next) regs (clamped on last kidx)
            const int kni = (kidx + 1 < nIter) ? kidx + 1 : kidx;
            const int ktn = ktOf(kni);
            const int kOffn = (ktn << 6) & 511;
            av0 = *(const s8v*)(srcA + kOffn);
            av1 = *(const s8v*)(srcA + kOffn + 8);

            // (3) issue B(next) DMA -> the NON-read buffer
            {
                const int k0n = ktn << 6;
                bf16* dstB = lB[(kidx + 1) & 1];
                #pragma unroll
                for (int c2 = 0; c2 < 4; ++c2) {
                    int rb = c2 * 8 + wvi;
                    int r = rb * 8 + row8;
                    int ls = sl8 ^ (r & 7);
                    gload16(Bp + (size_t)(n0 + r) * K + k0n + ls * 8, dstB + rb * 512);
                }
            }

            // (4) counted wait: B(cur)+A(next) complete; B(next) stays in flight.
            asm volatile("s_waitcnt vmcnt(4) lgkmcnt(0)" ::: "memory");
            asm volatile("s_barrier" ::: "memory");
            __builtin_amdgcn_sched_barrier(0);

            // (6) compute from lA + lB[kidx&1]
            const bf16* lBc = lB[kidx & 1];
            #pragma unroll
            for (int ks = 0; ks < 2; ++ks) {
                s8v afr[4], bfr[4];
                #pragma unroll
                for (int i = 0; i < 4; ++i) {
                    int ar = wr * 64 + i * 16 + r16;
                    afr[i] = *(const s8v*)((const char*)lA + ar * 128 + (((ks * 4 + g) ^ (ar & 7)) << 4));
                }
                #pragma unroll
                for (int j = 0; j < 4; ++j) {
                    int br = wc * 64 + j * 16 + r16;
                    bfr[j] = *(const s8v*)((const char*)lBc + br * 128 + (((ks * 4 + g) ^ (br & 7)) << 4));
                }
                #pragma unroll
                for (int i = 0; i < 4; ++i)
                    #pragma unroll
                    for (int j = 0; j < 4; ++j)
                        acc[i][j] = __builtin_amdgcn_mfma_f32_16x16x32_bf16(afr[i], bfr[j], acc[i][j], 0, 0, 0);
            }

            // (7) all reads done before next-iter staging
            asm volatile("s_barrier" ::: "memory");
        }

        asm volatile("s_waitcnt vmcnt(0)" ::: "memory");   // drain junk last-iter DMA
    }

    // ---- C write; mode0 self-reduces bias0 slice (same i order as old pool) ----
    #pragma unroll
    for (int i = 0; i < 4; ++i)
        #pragma unroll
        for (int j = 0; j < 4; ++j) {
            int cc = n0 + wc * 64 + j * 16 + r16;
            float bb = 0.f;
            if (mode == 0) {
                #pragma unroll
                for (int p = 0; p < 16; ++p) bb += bias0_part[(size_t)p * 512 + cc];
            }
            #pragma unroll
            for (int r = 0; r < 4; ++r) {
                int rr = m0 + wr * 64 + i * 16 + g * 4 + r;
                Cp[(size_t)rr * 512 + cc] = f2b(acc[i][j][r] + bb);
            }
        }
}

// ---------------------------------------------------------------- Fused amp-GEMM + gate + residual + LayerNorm (R14 version)
__global__ __launch_bounds__(512, 2) void amp_ln_kernel(
    const bf16* __restrict__ tout, const bf16* __restrict__ sout,
    const bf16* __restrict__ AWT,  const float* __restrict__ ampb,
    const float* __restrict__ x,   const float* __restrict__ gamma,
    const float* __restrict__ beta, float* __restrict__ out)
{
    __shared__ bf16 lA[64 * 64];     // 8 KB
    __shared__ bf16 lB[512 * 64];    // 64 KB
    __shared__ float red[64 * 16];   // 4 KB

    const int m0 = blockIdx.x << 6;
    const int tid = threadIdx.x;
    const int lane = tid & 63, wvi = tid >> 6;
    const int wc = wvi;
    const int r16 = lane & 15, g = lane >> 4;
    const int row8 = lane >> 3, sl8 = lane & 7;

    f4v acc[4][4];
    #pragma unroll
    for (int i = 0; i < 4; ++i)
        #pragma unroll
        for (int j = 0; j < 4; ++j) acc[i][j] = (f4v)0.f;

    for (int kt = 0; kt < 8; ++kt) {
        const int k0 = kt << 6;
        {
            int r = (wvi << 3) + row8;
            int ls = sl8 ^ (r & 7);
            gload16(tout + (size_t)(m0 + r) * 512 + k0 + ls * 8, &lA[wvi * 512]);
        }
        #pragma unroll
        for (int c2 = 0; c2 < 8; ++c2) {
            int r = c2 * 64 + (wvi << 3) + row8;
            int ls = sl8 ^ (r & 7);
            gload16(AWT + (size_t)r * 512 + k0 + ls * 8, &lB[c2 * 4096 + wvi * 512]);
        }
        __syncthreads();
        #pragma unroll
        for (int ks = 0; ks < 2; ++ks) {
            s8v afr[4], bfr[4];
            #pragma unroll
            for (int i = 0; i < 4; ++i) {
                int ar = i * 16 + r16;
                afr[i] = *(const s8v*)((const char*)lA + ar * 128 + (((ks * 4 + g) ^ (ar & 7)) << 4));
            }
            #pragma unroll
            for (int j = 0; j < 4; ++j) {
                int br = wc * 64 + j * 16 + r16;
                bfr[j] = *(const s8v*)((const char*)lB + br * 128 + (((ks * 4 + g) ^ (br & 7)) << 4));
            }
            #pragma unroll
            for (int i = 0; i < 4; ++i)
                #pragma unroll
                for (int j = 0; j < 4; ++j)
                    acc[i][j] = __builtin_amdgcn_mfma_f32_16x16x32_bf16(afr[i], bfr[j], acc[i][j], 0, 0, 0);
        }
        __syncthreads();
    }

    float ab[4], gm[4], bt2[4];
    #pragma unroll
    for (int j = 0; j < 4; ++j) {
        int cc = wc * 64 + j * 16 + r16;
        ab[j] = ampb[cc]; gm[j] = gamma[cc]; bt2[j] = beta[cc];
    }
    f4v s4[4], q4[4];
    #pragma unroll
    for (int i = 0; i < 4; ++i) { s4[i] = (f4v)0.f; q4[i] = (f4v)0.f; }

    #pragma unroll
    for (int i = 0; i < 4; ++i)
        #pragma unroll
        for (int j = 0; j < 4; ++j) {
            int cc = wc * 64 + j * 16 + r16;
            #pragma unroll
            for (int r = 0; r < 4; ++r) {
                size_t rr = (size_t)(m0 + i * 16 + g * 4 + r);
                float amp = 2.f * fsig(acc[i][j][r] + ab[j]);
                float y = b2f(tout[rr * 512 + cc]) + b2f(sout[rr * 512 + cc]) * amp + x[rr * 512 + cc];
                acc[i][j][r] = y;
                s4[i][r] += y; q4[i][r] += y * y;
            }
        }

    #pragma unroll
    for (int off = 1; off < 16; off <<= 1)
        #pragma unroll
        for (int i = 0; i < 4; ++i)
            #pragma unroll
            for (int r = 0; r < 4; ++r) {
                s4[i][r] += __shfl_xor(s4[i][r], off);
                q4[i][r] += __shfl_xor(q4[i][r], off);
            }
    if (r16 == 0) {
        #pragma unroll
        for (int i = 0; i < 4; ++i)
            #pragma unroll
            for (int r = 0; r < 4; ++r) {
                int row = i * 16 + g * 4 + r;
                red[row * 16 + wvi * 2]     = s4[i][r];
                red[row * 16 + wvi * 2 + 1] = q4[i][r];
            }
    }
    __syncthreads();
    if (tid < 64) {
        float ts = 0.f, tq = 0.f;
        #pragma unroll
        for (int w = 0; w < 8; ++w) { ts += red[tid * 16 + w * 2]; tq += red[tid * 16 + w * 2 + 1]; }
        float mu = ts * (1.f / 512.f);
        float var = tq * (1.f / 512.f) - mu * mu;
        red[tid * 16]     = mu;
        red[tid * 16 + 1] = rsqrtf(var + 1e-5f);
    }
    __syncthreads();

    #pragma unroll
    for (int i = 0; i < 4; ++i)
        #pragma unroll
        for (int r = 0; r < 4; ++r) {
            int row = i * 16 + g * 4 + r;
            float mu = red[row * 16], rs = red[row * 16 + 1];
            size_t rr = (size_t)(m0 + row);
            #pragma unroll
            for (int j = 0; j < 4; ++j) {
                int cc = wc * 64 + j * 16 + r16;
                out[rr * 512 + cc] = (acc[i][j][r] - mu) * rs * gm[j] + bt2[j];
            }
        }
}

// ----------------------------------------------------------------
extern "C" void kernel_launch(void* const* d_in, const int* in_sizes, int n_in,
                              void* d_out, int out_size, void* d_ws, size_t ws_size,
                              hipStream_t stream)
{
    const float* x     = (const float*)d_in[0];
    const float* tcw   = (const float*)d_in[1];
    const float* tcb   = (const float*)d_in[2];
    const float* scw   = (const float*)d_in[3];
    const float* scb   = (const float*)d_in[4];
    const float* lcw   = (const float*)d_in[5];
    const float* lcb   = (const float*)d_in[6];
    const float* cheby = (const float*)d_in[7];
    const float* hw1   = (const float*)d_in[8];
    const float* hb1   = (const float*)d_in[9];
    const float* hw2   = (const float*)d_in[10];
    const float* hb2   = (const float*)d_in[11];
    const float* ampw  = (const float*)d_in[12];
    const float* ampb  = (const float*)d_in[13];
    const float* wav   = (const float*)d_in[14];
    const float* lng   = (const float*)d_in[15];
    const float* lnb   = (const float*)d_in[16];
    float* out = (float*)d_out;

    char* ws = (char*)d_ws;
    size_t off = 0;
    auto alloc = [&](size_t bytes) -> char* {
        char* p = ws + off;
        off += (bytes + 255) & ~(size_t)255;
        return p;
    };
    bf16*  xt         = (bf16*)alloc((size_t)M_ * 512 * 2);
    bf16*  sctx       = (bf16*)alloc((size_t)M_ * 512 * 2);
    bf16*  tout       = (bf16*)alloc((size_t)M_ * 512 * 2);
    bf16*  sout       = (bf16*)alloc((size_t)M_ * 512 * 2);
    bf16*  CCT        = (bf16*)alloc((size_t)512 * 1536 * 2);
    bf16*  WWT        = (bf16*)alloc((size_t)512 * 2048 * 2);
    bf16*  AWT        = (bf16*)alloc((size_t)512 * 512 * 2);
    float* bias0_part = (float*)alloc((size_t)16 * 512 * 4);
    float* slope_part = (float*)alloc((size_t)NCHUNK * B_ * C_ * 4);
    float* value_part = (float*)alloc((size_t)NCHUNK * B_ * C_ * 4);

    front_kernel<<<2560, 256, 0, stream>>>(wav, ampw, cheby, x,
                                           tcw, tcb, scw, scb, lcw, lcb,
                                           WWT, AWT, CCT, bias0_part,
                                           xt, sctx, slope_part, value_part);
    gemm_big_kernel<<<512, 512, 0, stream>>>(xt, sctx, CCT, WWT,
                                             slope_part, value_part,
                                             hw1, hb1, hw2, hb2, bias0_part,
                                             tout, sout);
    amp_ln_kernel<<<256, 512, 0, stream>>>(tout, sout, AWT, ampb, x, lng, lnb, out);
}

// Round 19
// 162.894 us; speedup vs baseline: 1.2409x; 1.2409x over previous
//
#include <hip/hip_runtime.h>
#include <hip/hip_bf16.h>
#include <math.h>

typedef __hip_bfloat16 bf16;
typedef __attribute__((ext_vector_type(8))) short s8v;   // 8 bf16 (4 VGPRs)
typedef __attribute__((ext_vector_type(4))) float f4v;

#define B_   16
#define T_   1024
#define C_   512
#define M_   (B_*T_)      // 16384
#define NW_  4
#define KWIN 25
#define TCHUNK 16
#define NCHUNK (T_/TCHUNK)   // 64

__device__ __forceinline__ float b2f(bf16 v){ return __bfloat162float(v); }
__device__ __forceinline__ bf16  f2b(float v){ return __float2bfloat16(v); }

__device__ __forceinline__ float ftanh(float x){
    float e = __expf(2.f * x);
    return 1.f - 2.f * __builtin_amdgcn_rcpf(e + 1.f);
}
__device__ __forceinline__ float fsig(float x){
    return __builtin_amdgcn_rcpf(1.f + __expf(-x));
}

// async global->LDS, 16B per lane
__device__ __forceinline__ void gload16(const bf16* g, bf16* l) {
    __builtin_amdgcn_global_load_lds(
        (const __attribute__((address_space(1))) void*)g,
        (__attribute__((address_space(3))) void*)l, 16, 0, 0);
}

// ---------------------------------------------------------------- K0: prep (blocks 0..2047) + decomp (blocks 2048..3071)
__global__ __launch_bounds__(256) void front_kernel(
    const float* __restrict__ wav,  const float* __restrict__ ampw,
    const float* __restrict__ cheby, const float* __restrict__ w1,
    const float* __restrict__ x,
    const float* __restrict__ tcw, const float* __restrict__ tcb,
    const float* __restrict__ scw, const float* __restrict__ scb,
    const float* __restrict__ lcw, const float* __restrict__ lcb,
    bf16* __restrict__ WWT, bf16* __restrict__ AWT, bf16* __restrict__ CCT,
    float* __restrict__ bias0_part, float* __restrict__ w1t,
    bf16* __restrict__ xt, bf16* __restrict__ sctx,
    float* __restrict__ slope_part, float* __restrict__ value_part)
{
    const int blk = blockIdx.x;

    if (blk < 2048) {
        // ================= PREP =================
        __shared__ float t0[32][33], t1[32][33], t2[32][33], t3[32][33];
        const int tx = threadIdx.x & 31, ty = threadIdx.x >> 5;

        if (blk < 1280) {
            const int z = blk >> 8, rem = blk & 255;
            const int ct = (rem & 15) * 32, ot = (rem >> 4) * 32;
            const float* src = (z < 4) ? wav + (size_t)z * 262144 : ampw;
            #pragma unroll
            for (int r = 0; r < 32; r += 8)
                t0[ty + r][tx] = src[(size_t)(ct + ty + r) * 512 + ot + tx];
            __syncthreads();
            #pragma unroll
            for (int r = 0; r < 32; r += 8) {
                int o = ot + ty + r, c = ct + tx;
                bf16 v = f2b(t0[tx][ty + r]);
                if (z < 4) WWT[(size_t)o * 2048 + z * 512 + c] = v;
                else       AWT[(size_t)o * 512 + c] = v;
            }
        } else if (blk < 1536) {
            const int rem = blk - 1280;
            const int ct = (rem & 15) * 32, ot = (rem >> 4) * 32;
            #pragma unroll
            for (int r = 0; r < 32; r += 8) {
                float4 w = *(const float4*)&cheby[(size_t)(ct + ty + r) * 2048 + (size_t)(ot + tx) * 4];
                t0[ty + r][tx] = w.x - w.z;
                t1[ty + r][tx] = w.y - 3.f * w.w;
                t2[ty + r][tx] = 2.f * w.z;
                t3[ty + r][tx] = 4.f * w.w;
            }
            __syncthreads();
            #pragma unroll
            for (int r = 0; r < 32; r += 8) {
                int o = ot + ty + r, c = ct + tx;
                size_t base = (size_t)o * 1536 + c;
                CCT[base]        = f2b(t1[tx][ty + r]);
                CCT[base + 512]  = f2b(t2[tx][ty + r]);
                CCT[base + 1024] = f2b(t3[tx][ty + r]);
            }
            if (threadIdx.x < 32) {
                float s = 0.f;
                #pragma unroll
                for (int cr = 0; cr < 32; ++cr) s += t0[cr][threadIdx.x];
                bias0_part[(size_t)(rem & 15) * 512 + ot + threadIdx.x] = s;
            }
        } else {
            const int rem = blk - 1536;
            const int bo = rem & 15, bj = rem >> 4;
            #pragma unroll
            for (int r = 0; r < 32; r += 8)
                t0[ty + r][tx] = w1[(size_t)(bj * 32 + ty + r) * 512 + bo * 32 + tx];
            __syncthreads();
            #pragma unroll
            for (int r = 0; r < 32; r += 8)
                w1t[(size_t)(bo * 32 + ty + r) * 1024 + bj * 32 + tx] = t0[tx][ty + r];
        }
        return;
    }

    // ================= DECOMP =================
    const int dblk  = blk - 2048;
    const int c     = threadIdx.x * 2;
    const int chunk = dblk & 63;
    const int b     = dblk >> 6;
    const int t0i   = chunk * TCHUNK;
    const float* xb = x + (size_t)b * T_ * C_ + c;

    float w0t[2], w1t_[2], w2t[2], bt[2], w0s[2], w1s[2], w2s[2], bs[2], w0l[2], w1l[2], w2l[2], bl[2];
    #pragma unroll
    for (int e = 0; e < 2; ++e) {
        w0t[e]=tcw[(c+e)*3+0]; w1t_[e]=tcw[(c+e)*3+1]; w2t[e]=tcw[(c+e)*3+2]; bt[e]=tcb[c+e];
        w0s[e]=scw[(c+e)*3+0]; w1s[e]=scw[(c+e)*3+1]; w2s[e]=scw[(c+e)*3+2]; bs[e]=scb[c+e];
        w0l[e]=lcw[(c+e)*3+0]; w1l[e]=lcw[(c+e)*3+1]; w2l[e]=lcw[(c+e)*3+2]; bl[e]=lcb[c+e];
    }

    const float inv = 1.f / KWIN;
    float S0 = 0.f, S1 = 0.f;
    float trm[2], tr0[2], xm[2], x0v[2], sAcc[2] = {0.f,0.f}, vAcc[2] = {0.f,0.f};

    auto BODY = [&](int t, float2 an, float2 dn, bool adv) {
        float trp[2], xp[2];
        if (adv) {
            S0 += an.x - dn.x; S1 += an.y - dn.y;
            trp[0] = S0 * inv; trp[1] = S1 * inv;
            xp[0] = an.x; xp[1] = an.y;
        } else {
            trp[0] = tr0[0]; trp[1] = tr0[1];
            xp[0] = x0v[0];  xp[1] = x0v[1];
        }
        union { bf16 h[2]; unsigned u; } u1, usc;
        #pragma unroll
        for (int e = 0; e < 2; ++e) {
            float tctx = w0t[e]*trm[e] + w1t_[e]*tr0[e] + w2t[e]*trp[e] + bt[e];
            float sm = xm[e]-trm[e], s0 = x0v[e]-tr0[e], sp = xp[e]-trp[e];
            float sv = w0s[e]*sm + w1s[e]*s0 + w2s[e]*sp + bs[e];
            float sl = w0l[e]*trm[e] + w1l[e]*tr0[e] + w2l[e]*trp[e] + bl[e];
            sAcc[e] += sl; vAcc[e] += tr0[e];
            u1.h[e] = f2b(ftanh(tctx)); usc.h[e] = f2b(sv);
            trm[e] = tr0[e]; tr0[e] = trp[e]; xm[e] = x0v[e]; x0v[e] = xp[e];
        }
        size_t m = (size_t)b * T_ + t;
        *(unsigned*)&xt[m * C_ + c]   = u1.u;
        *(unsigned*)&sctx[m * C_ + c] = usc.u;
    };

    if (chunk >= 2 && chunk <= NCHUNK - 2) {
        const float* p = xb + (size_t)(t0i - KWIN) * C_;
        #pragma unroll
        for (int i = 0; i < KWIN; ++i) {
            float2 v = *(const float2*)(p + (size_t)i * C_);
            S0 += v.x; S1 += v.y;
        }
        trm[0] = S0 * inv; trm[1] = S1 * inv;
        float2 a = *(const float2*)(p + (size_t)KWIN * C_);
        float2 d = *(const float2*)p;
        S0 += a.x - d.x; S1 += a.y - d.y;
        tr0[0] = S0 * inv; tr0[1] = S1 * inv;
        float2 vm = *(const float2*)(p + (size_t)(KWIN - 1) * C_);
        xm[0] = vm.x; xm[1] = vm.y;
        x0v[0] = a.x; x0v[1] = a.y;

        #pragma unroll
        for (int tt = 0; tt < TCHUNK; ++tt) {
            float2 an = *(const float2*)(p + (size_t)(KWIN + 1 + tt) * C_);
            float2 dn = *(const float2*)(p + (size_t)(1 + tt) * C_);
            BODY(t0i + tt, an, dn, true);
        }
    } else {
        auto X = [&](int i) -> float2 {
            i = i < 0 ? 0 : (i > T_ - 1 ? T_ - 1 : i);
            return *(const float2*)&xb[(size_t)i * C_];
        };
        int j0 = (t0i > 0) ? (t0i - 1) : 0;
        #pragma unroll
        for (int i = j0 - (KWIN - 1); i <= j0; ++i) { float2 v = X(i); S0 += v.x; S1 += v.y; }
        trm[0] = S0 * inv; trm[1] = S1 * inv;
        if (t0i > 0) {
            float2 a = X(t0i), d = X(t0i - KWIN);
            S0 += a.x - d.x; S1 += a.y - d.y;
            tr0[0] = S0 * inv; tr0[1] = S1 * inv;
        } else { tr0[0] = trm[0]; tr0[1] = trm[1]; }
        { float2 v = X(t0i - 1); xm[0] = v.x; xm[1] = v.y; }
        { float2 v = X(t0i);     x0v[0] = v.x; x0v[1] = v.y; }

        #pragma unroll
        for (int tt = 0; tt < TCHUNK; ++tt) {
            int t = t0i + tt, tn = t + 1;
            bool adv = (tn <= T_ - 1);
            float2 an = make_float2(0.f, 0.f), dn = make_float2(0.f, 0.f);
            if (adv) { an = X(tn); dn = X(tn - KWIN); }
            BODY(t, an, dn, adv);
        }
    }
    int pidx = (chunk * B_ + b) * C_ + c;
    *(float2*)&slope_part[pidx] = make_float2(sAcc[0], sAcc[1]);
    *(float2*)&value_part[pidx] = make_float2(vAcc[0], vAcc[1]);
}

// ---------------------------------------------------------------- K2a: pool reduce -> pc[16][1024]; also finish bias0
__global__ __launch_bounds__(256) void pool_kernel(
    const float* __restrict__ slope_part, const float* __restrict__ value_part,
    const float* __restrict__ bias0_part,
    float* __restrict__ pc, float* __restrict__ bias0)
{
    int idx = blockIdx.x * 256 + threadIdx.x;   // 16384
    int b = idx >> 10, j = idx & 1023;
    int c = j & 511;
    const float* src = (j < 512) ? slope_part : value_part;
    float s = 0.f;
    #pragma unroll 8
    for (int ch = 0; ch < NCHUNK; ++ch) s += src[(ch * B_ + b) * C_ + c];
    pc[idx] = s * (1.f / T_);
    if (idx < 512) {
        float t = 0.f;
        #pragma unroll
        for (int i = 0; i < 16; ++i) t += bias0_part[(size_t)i * 512 + idx];
        bias0[idx] = t;
    }
}

// ---------------------------------------------------------------- K2b: h = silu(pc @ w1 + b1); 1 block per o
__global__ __launch_bounds__(256) void hyper1_kernel(
    const float* __restrict__ pc, const float* __restrict__ w1t,
    const float* __restrict__ b1, float* __restrict__ h)
{
    const int o = blockIdx.x, t = threadIdx.x;
    const float4 w = *(const float4*)&w1t[(size_t)o * 1024 + t * 4];
    float acc[16];
    #pragma unroll
    for (int b = 0; b < 16; ++b) {
        float4 p = *(const float4*)&pc[(size_t)b * 1024 + t * 4];
        acc[b] = w.x * p.x + w.y * p.y + w.z * p.z + w.w * p.w;
    }
    #pragma unroll
    for (int off = 32; off >= 1; off >>= 1)
        #pragma unroll
        for (int b = 0; b < 16; ++b) acc[b] += __shfl_down(acc[b], off);
    __shared__ float red[4][16];
    int lane = t & 63, wv = t >> 6;
    if (lane == 0)
        #pragma unroll
        for (int b = 0; b < 16; ++b) red[wv][b] = acc[b];
    __syncthreads();
    if (t < 16) {
        float s = red[0][t] + red[1][t] + red[2][t] + red[3][t] + b1[o];
        h[(size_t)t * 512 + o] = s / (1.f + expf(-s));
    }
}

// ---------------------------------------------------------------- K2c: params -> dyn_a, dyn_b
__global__ __launch_bounds__(128) void hyper2_kernel(
    const float* __restrict__ h, const float* __restrict__ w2,
    const float* __restrict__ b2, float* __restrict__ dyn_a, float* __restrict__ dyn_b)
{
    __shared__ float pp[16][8];
    const int t = threadIdx.x, b = t >> 3, o = t & 7;
    float acc = b2[o];
    #pragma unroll 4
    for (int j = 0; j < 512; ++j) acc += h[(size_t)b * 512 + j] * w2[j * 8 + o];
    pp[b][o] = acc;
    __syncthreads();
    if (t < 64) {
        int bb = t >> 2, w = t & 3;
        float pa = pp[bb][2 * w], pb = pp[bb][2 * w + 1];
        float sp = fmaxf(pa, 0.f) + log1pf(expf(-fabsf(pa)));
        dyn_a[bb * NW_ + w] = sp + 0.01f;
        dyn_b[bb * NW_ + w] = (1.f / (1.f + expf(-pb))) * (float)T_;
    }
}

// ---------------------------------------------------------------- Fused big GEMM (R14 config): 8-wave 128x256, PIPELINED +
// compacted alive-segment iteration. 80 KB LDS -> 2 blocks/CU, VGPR capped at 64.
__global__ __launch_bounds__(512, 4) void gemm_big_kernel(
    const bf16* __restrict__ xt, const bf16* __restrict__ sctxg,
    const bf16* __restrict__ CCT, const bf16* __restrict__ WWT,
    const float* __restrict__ dyn_a, const float* __restrict__ dyn_b,
    const float* __restrict__ bias0,
    bf16* __restrict__ tout, bf16* __restrict__ sout)
{
    __shared__ bf16 lA[128 * 64];        // 16 KB (first 16B reused as reduction scratch pre-loop)
    __shared__ bf16 lB[2][256 * 64];     // 64 KB double-buffered

    const int lin = blockIdx.x;
    const int swz = ((lin & 7) << 6) + (lin >> 3);   // bijective XCD swizzle, 512 blocks
    const int mode = swz & 1;
    const int rem = swz >> 1;
    const int nb = rem & 1, mb = rem >> 1;
    const int m0 = mb << 7, n0 = nb << 8;

    const bf16* Ap = mode ? sctxg : xt;   // both [M][512]
    const bf16* Bp = mode ? WWT : CCT;
    bf16* Cp = mode ? sout : tout;
    const int K = mode ? 2048 : 1536;

    const int tid = threadIdx.x;
    const int lane = tid & 63, wvi = tid >> 6;
    const int wr = wvi >> 2, wc = wvi & 3;          // 2m x 4n waves of 64x64
    const int r16 = lane & 15, g = lane >> 4;
    const int row8 = lane >> 3, sl8 = lane & 7;
    const int arow = tid >> 2, quad = tid & 3;      // A staging: 4 thr/row, 16 elems each

    // ---- psi in-reg + per-w alive reduction (mode1); build compacted segment list ----
    float4 p4 = make_float4(0.f, 0.f, 0.f, 0.f);
    int ordPacked = 0x210, nIter = 24;              // mode0: segments {0,1,2}
    if (mode) {
        int* wmaxsh = (int*)lA;
        if (tid < 4) wmaxsh[tid] = 0;
        __syncthreads();
        const int bIdx = m0 >> 10;
        const float tpos = (float)((m0 + arow) & 1023);
        float pv[4], am[4];
        #pragma unroll
        for (int w = 0; w < 4; ++w) {
            float z = (tpos - dyn_b[bIdx * 4 + w]) / dyn_a[bIdx * 4 + w];
            float z2 = z * z;
            pv[w] = (1.f - z2) * __expf(-0.5f * z2);
            am[w] = fabsf(pv[w]);
        }
        p4 = make_float4(pv[0], pv[1], pv[2], pv[3]);
        #pragma unroll
        for (int off = 32; off >= 1; off >>= 1)
            #pragma unroll
            for (int w = 0; w < 4; ++w) am[w] = fmaxf(am[w], __shfl_xor(am[w], off));
        if (lane == 0) {
            #pragma unroll
            for (int w = 0; w < 4; ++w) atomicMax(&wmaxsh[w], __float_as_int(am[w]));
        }
        __syncthreads();
        ordPacked = 0; int na = 0;
        #pragma unroll
        for (int w = 0; w < 4; ++w) {
            float f = __int_as_float(__builtin_amdgcn_readfirstlane(wmaxsh[w]));
            if (f > 1e-6f) { ordPacked |= w << (4 * na); ++na; }
        }
        nIter = na * 8;
        __syncthreads();   // scratch reads done before lA ds_writes
    }

    auto ktOf = [&](int kidx) -> int {
        int seg = (ordPacked >> ((kidx >> 3) * 4)) & 15;
        return seg * 8 + (kidx & 7);
    };

    const bf16* srcA = Ap + (size_t)(m0 + arow) * 512 + quad * 16;

    f4v acc[4][4];
    #pragma unroll
    for (int i = 0; i < 4; ++i)
        #pragma unroll
        for (int j = 0; j < 4; ++j) acc[i][j] = (f4v)0.f;

    if (nIter > 0) {
        // ---- prologue: A(k0) regs + B(k0) DMA ----
        const int ktp = ktOf(0);
        s8v av0 = *(const s8v*)(srcA + ((ktp << 6) & 511));
        s8v av1 = *(const s8v*)(srcA + ((ktp << 6) & 511) + 8);
        #pragma unroll
        for (int c2 = 0; c2 < 4; ++c2) {
            int rb = c2 * 8 + wvi;
            int r = rb * 8 + row8;
            int ls = sl8 ^ (r & 7);
            gload16(Bp + (size_t)(n0 + r) * K + (ktp << 6) + ls * 8, &lB[0][rb * 512]);
        }
        asm volatile("s_waitcnt vmcnt(4)" ::: "memory");   // A regs landed; B(k0) in flight

        for (int kidx = 0; kidx < nIter; ++kidx) {
            const int ktc = ktOf(kidx);
            const int wsel = ktc >> 3;
            const float sc = wsel == 0 ? p4.x : wsel == 1 ? p4.y : wsel == 2 ? p4.z : p4.w;

            // (1) transform A regs -> swizzled ds_write into lA
            #pragma unroll
            for (int j2 = 0; j2 < 2; ++j2) {
                s8v a = j2 ? av1 : av0;
                s8v ov;
                if (mode == 0) {
                    if (wsel == 0) ov = a;
                    else {
                        #pragma unroll
                        for (int e = 0; e < 8; ++e) {
                            float v = b2f(((const bf16*)&a)[e]);
                            float vv = v * v;
                            ((bf16*)&ov)[e] = f2b(wsel == 1 ? vv : vv * v);
                        }
                    }
                } else {
                    #pragma unroll
                    for (int e = 0; e < 8; ++e)
                        ((bf16*)&ov)[e] = f2b(b2f(((const bf16*)&a)[e]) * sc);
                }
                int q = quad * 2 + j2;
                *(s8v*)&lA[arow * 64 + ((q ^ (arow & 7)) << 3)] = ov;
            }

            // (2) prefetch A(next) regs (clamped on last kidx)
            const int kni = (kidx + 1 < nIter) ? kidx + 1 : kidx;
            const int ktn = ktOf(kni);
            const int kOffn = (ktn << 6) & 511;
            av0 = *(const s8v*)(srcA + kOffn);
            av1 = *(const s8v*)(srcA + kOffn + 8);

            // (3) issue B(next) DMA -> the NON-read buffer
            {
                const int k0n = ktn << 6;
                bf16* dstB = lB[(kidx + 1) & 1];
                #pragma unroll
                for (int c2 = 0; c2 < 4; ++c2) {
                    int rb = c2 * 8 + wvi;
                    int r = rb * 8 + row8;
                    int ls = sl8 ^ (r & 7);
                    gload16(Bp + (size_t)(n0 + r) * K + k0n + ls * 8, dstB + rb * 512);
                }
            }

            // (4) counted wait: B(cur)+A(next) complete; B(next) stays in flight.
            asm volatile("s_waitcnt vmcnt(4) lgkmcnt(0)" ::: "memory");
            asm volatile("s_barrier" ::: "memory");
            __builtin_amdgcn_sched_barrier(0);

            // (6) compute from lA + lB[kidx&1]
            const bf16* lBc = lB[kidx & 1];
            #pragma unroll
            for (int ks = 0; ks < 2; ++ks) {
                s8v afr[4], bfr[4];
                #pragma unroll
                for (int i = 0; i < 4; ++i) {
                    int ar = wr * 64 + i * 16 + r16;
                    afr[i] = *(const s8v*)((const char*)lA + ar * 128 + (((ks * 4 + g) ^ (ar & 7)) << 4));
                }
                #pragma unroll
                for (int j = 0; j < 4; ++j) {
                    int br = wc * 64 + j * 16 + r16;
                    bfr[j] = *(const s8v*)((const char*)lBc + br * 128 + (((ks * 4 + g) ^ (br & 7)) << 4));
                }
                #pragma unroll
                for (int i = 0; i < 4; ++i)
                    #pragma unroll
                    for (int j = 0; j < 4; ++j)
                        acc[i][j] = __builtin_amdgcn_mfma_f32_16x16x32_bf16(afr[i], bfr[j], acc[i][j], 0, 0, 0);
            }

            // (7) all reads done before next-iter staging
            asm volatile("s_barrier" ::: "memory");
        }

        asm volatile("s_waitcnt vmcnt(0)" ::: "memory");   // drain junk last-iter DMA
    }

    // ---- C write (D: col=lane&15, row=(lane>>4)*4+r), + bias on mode0 ----
    #pragma unroll
    for (int i = 0; i < 4; ++i)
        #pragma unroll
        for (int j = 0; j < 4; ++j) {
            int cc = n0 + wc * 64 + j * 16 + r16;
            float bb = (mode == 0) ? bias0[cc] : 0.f;
            #pragma unroll
            for (int r = 0; r < 4; ++r) {
                int rr = m0 + wr * 64 + i * 16 + g * 4 + r;
                Cp[(size_t)rr * 512 + cc] = f2b(acc[i][j][r] + bb);
            }
        }
}

// ---------------------------------------------------------------- Fused amp-GEMM + gate + residual + LayerNorm (R14 version)
__global__ __launch_bounds__(512, 2) void amp_ln_kernel(
    const bf16* __restrict__ tout, const bf16* __restrict__ sout,
    const bf16* __restrict__ AWT,  const float* __restrict__ ampb,
    const float* __restrict__ x,   const float* __restrict__ gamma,
    const float* __restrict__ beta, float* __restrict__ out)
{
    __shared__ bf16 lA[64 * 64];     // 8 KB
    __shared__ bf16 lB[512 * 64];    // 64 KB
    __shared__ float red[64 * 16];   // 4 KB

    const int m0 = blockIdx.x << 6;
    const int tid = threadIdx.x;
    const int lane = tid & 63, wvi = tid >> 6;
    const int wc = wvi;
    const int r16 = lane & 15, g = lane >> 4;
    const int row8 = lane >> 3, sl8 = lane & 7;

    f4v acc[4][4];
    #pragma unroll
    for (int i = 0; i < 4; ++i)
        #pragma unroll
        for (int j = 0; j < 4; ++j) acc[i][j] = (f4v)0.f;

    for (int kt = 0; kt < 8; ++kt) {
        const int k0 = kt << 6;
        {
            int r = (wvi << 3) + row8;
            int ls = sl8 ^ (r & 7);
            gload16(tout + (size_t)(m0 + r) * 512 + k0 + ls * 8, &lA[wvi * 512]);
        }
        #pragma unroll
        for (int c2 = 0; c2 < 8; ++c2) {
            int r = c2 * 64 + (wvi << 3) + row8;
            int ls = sl8 ^ (r & 7);
            gload16(AWT + (size_t)r * 512 + k0 + ls * 8, &lB[c2 * 4096 + wvi * 512]);
        }
        __syncthreads();
        #pragma unroll
        for (int ks = 0; ks < 2; ++ks) {
            s8v afr[4], bfr[4];
            #pragma unroll
            for (int i = 0; i < 4; ++i) {
                int ar = i * 16 + r16;
                afr[i] = *(const s8v*)((const char*)lA + ar * 128 + (((ks * 4 + g) ^ (ar & 7)) << 4));
            }
            #pragma unroll
            for (int j = 0; j < 4; ++j) {
                int br = wc * 64 + j * 16 + r16;
                bfr[j] = *(const s8v*)((const char*)lB + br * 128 + (((ks * 4 + g) ^ (br & 7)) << 4));
            }
            #pragma unroll
            for (int i = 0; i < 4; ++i)
                #pragma unroll
                for (int j = 0; j < 4; ++j)
                    acc[i][j] = __builtin_amdgcn_mfma_f32_16x16x32_bf16(afr[i], bfr[j], acc[i][j], 0, 0, 0);
        }
        __syncthreads();
    }

    float ab[4], gm[4], bt2[4];
    #pragma unroll
    for (int j = 0; j < 4; ++j) {
        int cc = wc * 64 + j * 16 + r16;
        ab[j] = ampb[cc]; gm[j] = gamma[cc]; bt2[j] = beta[cc];
    }
    f4v s4[4], q4[4];
    #pragma unroll
    for (int i = 0; i < 4; ++i) { s4[i] = (f4v)0.f; q4[i] = (f4v)0.f; }

    #pragma unroll
    for (int i = 0; i < 4; ++i)
        #pragma unroll
        for (int j = 0; j < 4; ++j) {
            int cc = wc * 64 + j * 16 + r16;
            #pragma unroll
            for (int r = 0; r < 4; ++r) {
                size_t rr = (size_t)(m0 + i * 16 + g * 4 + r);
                float amp = 2.f * fsig(acc[i][j][r] + ab[j]);
                float y = b2f(tout[rr * 512 + cc]) + b2f(sout[rr * 512 + cc]) * amp + x[rr * 512 + cc];
                acc[i][j][r] = y;
                s4[i][r] += y; q4[i][r] += y * y;
            }
        }

    #pragma unroll
    for (int off = 1; off < 16; off <<= 1)
        #pragma unroll
        for (int i = 0; i < 4; ++i)
            #pragma unroll
            for (int r = 0; r < 4; ++r) {
                s4[i][r] += __shfl_xor(s4[i][r], off);
                q4[i][r] += __shfl_xor(q4[i][r], off);
            }
    if (r16 == 0) {
        #pragma unroll
        for (int i = 0; i < 4; ++i)
            #pragma unroll
            for (int r = 0; r < 4; ++r) {
                int row = i * 16 + g * 4 + r;
                red[row * 16 + wvi * 2]     = s4[i][r];
                red[row * 16 + wvi * 2 + 1] = q4[i][r];
            }
    }
    __syncthreads();
    if (tid < 64) {
        float ts = 0.f, tq = 0.f;
        #pragma unroll
        for (int w = 0; w < 8; ++w) { ts += red[tid * 16 + w * 2]; tq += red[tid * 16 + w * 2 + 1]; }
        float mu = ts * (1.f / 512.f);
        float var = tq * (1.f / 512.f) - mu * mu;
        red[tid * 16]     = mu;
        red[tid * 16 + 1] = rsqrtf(var + 1e-5f);
    }
    __syncthreads();

    #pragma unroll
    for (int i = 0; i < 4; ++i)
        #pragma unroll
        for (int r = 0; r < 4; ++r) {
            int row = i * 16 + g * 4 + r;
            float mu = red[row * 16], rs = red[row * 16 + 1];
            size_t rr = (size_t)(m0 + row);
            #pragma unroll
            for (int j = 0; j < 4; ++j) {
                int cc = wc * 64 + j * 16 + r16;
                out[rr * 512 + cc] = (acc[i][j][r] - mu) * rs * gm[j] + bt2[j];
            }
        }
}

// ----------------------------------------------------------------
extern "C" void kernel_launch(void* const* d_in, const int* in_sizes, int n_in,
                              void* d_out, int out_size, void* d_ws, size_t ws_size,
                              hipStream_t stream)
{
    const float* x     = (const float*)d_in[0];
    const float* tcw   = (const float*)d_in[1];
    const float* tcb   = (const float*)d_in[2];
    const float* scw   = (const float*)d_in[3];
    const float* scb   = (const float*)d_in[4];
    const float* lcw   = (const float*)d_in[5];
    const float* lcb   = (const float*)d_in[6];
    const float* cheby = (const float*)d_in[7];
    const float* hw1   = (const float*)d_in[8];
    const float* hb1   = (const float*)d_in[9];
    const float* hw2   = (const float*)d_in[10];
    const float* hb2   = (const float*)d_in[11];
    const float* ampw  = (const float*)d_in[12];
    const float* ampb  = (const float*)d_in[13];
    const float* wav   = (const float*)d_in[14];
    const float* lng   = (const float*)d_in[15];
    const float* lnb   = (const float*)d_in[16];
    float* out = (float*)d_out;

    char* ws = (char*)d_ws;
    size_t off = 0;
    auto alloc = [&](size_t bytes) -> char* {
        char* p = ws + off;
        off += (bytes + 255) & ~(size_t)255;
        return p;
    };
    bf16*  xt         = (bf16*)alloc((size_t)M_ * 512 * 2);
    bf16*  sctx       = (bf16*)alloc((size_t)M_ * 512 * 2);
    bf16*  tout       = (bf16*)alloc((size_t)M_ * 512 * 2);
    bf16*  sout       = (bf16*)alloc((size_t)M_ * 512 * 2);
    bf16*  CCT        = (bf16*)alloc((size_t)512 * 1536 * 2);
    bf16*  WWT        = (bf16*)alloc((size_t)512 * 2048 * 2);
    bf16*  AWT        = (bf16*)alloc((size_t)512 * 512 * 2);
    float* W1T        = (float*)alloc((size_t)512 * 1024 * 4);
    float* bias0_part = (float*)alloc((size_t)16 * 512 * 4);
    float* bias0      = (float*)alloc(512 * 4);
    float* slope_part = (float*)alloc((size_t)NCHUNK * B_ * C_ * 4);
    float* value_part = (float*)alloc((size_t)NCHUNK * B_ * C_ * 4);
    float* pc         = (float*)alloc(B_ * 1024 * 4);
    float* hbuf       = (float*)alloc(B_ * C_ * 4);
    float* dyn_a      = (float*)alloc(B_ * NW_ * 4);
    float* dyn_b      = (float*)alloc(B_ * NW_ * 4);

    front_kernel<<<3072, 256, 0, stream>>>(wav, ampw, cheby, hw1, x,
                                           tcw, tcb, scw, scb, lcw, lcb,
                                           WWT, AWT, CCT, bias0_part, W1T,
                                           xt, sctx, slope_part, value_part);
    pool_kernel<<<64, 256, 0, stream>>>(slope_part, value_part, bias0_part, pc, bias0);
    hyper1_kernel<<<512, 256, 0, stream>>>(pc, W1T, hb1, hbuf);
    hyper2_kernel<<<1, 128, 0, stream>>>(hbuf, hw2, hb2, dyn_a, dyn_b);
    gemm_big_kernel<<<512, 512, 0, stream>>>(xt, sctx, CCT, WWT, dyn_a, dyn_b, bias0, tout, sout);
    amp_ln_kernel<<<256, 512, 0, stream>>>(tout, sout, AWT, ampb, x, lng, lnb, out);
}